// Round 1
// baseline (2643.079 us; speedup 1.0000x reference)
//
#include <hip/hip_runtime.h>
#include <hip/hip_bf16.h>

#define T_SEQ 512
#define BATCH 256
#define HID   1024
#define EMBD  256
#define NCLS  10

typedef __bf16 bf16x8 __attribute__((ext_vector_type(8)));
typedef float  floatx16 __attribute__((ext_vector_type(16)));
typedef float  floatx2 __attribute__((ext_vector_type(2)));
typedef unsigned short ushortx8 __attribute__((ext_vector_type(8)));

__device__ __forceinline__ unsigned int f2bf(float f) {
    unsigned int u = __builtin_bit_cast(unsigned int, f);
    u += 0x7fffu + ((u >> 16) & 1u);
    return u >> 16;
}
__device__ __forceinline__ float sig_fast(float x) {
    return __builtin_amdgcn_rcpf(1.0f + __expf(-x));
}
__device__ __forceinline__ float tanh_fast(float x) {
    return 1.0f - 2.0f * __builtin_amdgcn_rcpf(1.0f + __expf(2.0f * x));
}

// -------------------- prep: XW[tok][gate][n] = emb[tok] @ Wx_gate + b_gate ---
__global__ void prep_xw_kernel(const float* __restrict__ emb,
                               const float* __restrict__ wgx, const float* __restrict__ wix,
                               const float* __restrict__ wfx, const float* __restrict__ wox,
                               const float* __restrict__ bg,  const float* __restrict__ bi,
                               const float* __restrict__ bf,  const float* __restrict__ bo,
                               float* __restrict__ XW) {
    int gid = blockIdx.x * blockDim.x + threadIdx.x;     // 3*4*1024 = 12288
    if (gid >= 3 * 4 * HID) return;
    int tok  = gid >> 12;
    int gate = (gid >> 10) & 3;
    int n    = gid & 1023;
    const float* W = gate == 0 ? wgx : gate == 1 ? wix : gate == 2 ? wfx : wox;
    const float* B = gate == 0 ? bg  : gate == 1 ? bi  : gate == 2 ? bf  : bo;
    float acc = B[n];
    const float* e = emb + tok * EMBD;
    for (int k = 0; k < EMBD; ++k) acc += e[k] * W[k * HID + n];
    XW[gid] = acc;
}

// ---- prep: Wt in 32x32x16 MFMA B-fragment order, (gate-pair, k-quarter) waves.
// Wave (w, gp, kq) handles gates {2gp, 2gp+1} over ksteps kk = kq*16 + i.
// frag = (((w*2+gp)*4+kq)*16 + i)*2 + gsub ; Wt[frag*512 + lane*8 + e]
//   = bf16( W_{2gp+gsub}[k = kk*16 + (lane>>5)*8 + e][j = w*32 + (lane&31)] )
__global__ void prep_w_kernel(const float* __restrict__ wgh, const float* __restrict__ wih,
                              const float* __restrict__ wfh, const float* __restrict__ woh,
                              unsigned short* __restrict__ Wt) {
    int bid  = blockIdx.x;                // 8192 = w(32) x gp(2) x kq(4) x i(16) x gsub(2)
    int gsub = bid & 1;
    int i    = (bid >> 1) & 15;
    int kq   = (bid >> 5) & 3;
    int gp   = (bid >> 7) & 1;
    int w    = bid >> 8;
    int g    = gp * 2 + gsub;
    const float* W = g == 0 ? wgh : g == 1 ? wih : g == 2 ? wfh : woh;
    int lane = threadIdx.x;               // 64
    int j    = w * 32 + (lane & 31);
    int kk   = kq * 16 + i;
    int k0   = kk * 16 + (lane >> 5) * 8;
    ushortx8 o8;
    #pragma unroll
    for (int e = 0; e < 8; ++e) o8[e] = (unsigned short)f2bf(W[(k0 + e) * HID + j]);
    int frag = (((w * 2 + gp) * 4 + kq) * 16 + i) * 2 + gsub;
    *(ushortx8*)&Wt[frag * 512 + lane * 8] = o8;
}

// -------------------- persistent recurrent kernel ---------------------------
// 256 WGs x 512 threads. grp = blockIdx%8 owns 32 batch rows; w = blockIdx/8
// owns 32 hidden cols.
//
// R8 restructure: waves are (gate-pair gp, k-quarter kq) instead of (gate,
// k-half). Each wave reads each A-fragment ONCE for two gates, and reads it
// DIRECTLY from global (h lives in the XCD-local L2; producers use plain
// write-back stores). This deletes the hs LDS staging array, the 64 KB
// L2->VGPR->LDS round trip, one barrier, and the 256 KB/step of redundant
// LDS A-reads that made the GEMM phase LDS-BW-bound (3200 cyc) instead of
// MFMA-bound (2067 cyc).
//
// Coherence for direct A-loads (local path): producer stores are workgroup-
// scope (write-back into the shared XCD L2). Consumer L1 may hold stale lines
// (hbuf parity reused every 2 steps), so each wave issues `buffer_inv`
// (vector-L1 invalidate; L1 is write-through => cannot lose data, does not
// touch L2) once per step before its A-loads. The gp-pair redundancy (2 waves
// read the same k-quarter) is then absorbed by L1. Fallback (non-co-XCD):
// system-scope atomic loads bypass L1+L2 as before.
__global__ __launch_bounds__(512, 2)
void lstm_kernel(const int* __restrict__ x, const float* __restrict__ XW,
                 const unsigned short* __restrict__ Wt,
                 unsigned int* __restrict__ hbuf32, int* __restrict__ flags,
                 int* __restrict__ xflag) {
    __shared__ float gbuf[16 * 32 * 36];          // [gate][kq][row][col+pad] (73728 B)
    __shared__ float xwl[384];                    // [tok][gate][32 cols]     (1536 B)
    __shared__ unsigned char xtok[32 * 512];      // tokens, byte-packed      (16384 B)
    __shared__ int use_local_sh;

    const int tid  = threadIdx.x;
    const int grp  = blockIdx.x & 7;
    const int w    = blockIdx.x >> 3;
    const int wv   = tid >> 6;
    const int gp   = wv >> 2;                  // gate pair: gates {2gp, 2gp+1}
    const int kq   = wv & 3;                   // k-quarter: kk in [kq*16, kq*16+16)
    const int lane = tid & 63;
    const int m32  = lane & 31;
    const int hv5  = lane >> 5;

    // ---- XCD-locality check (one-time, system-scope => placement-safe) ----
    {
        int xcc = 0;
        asm volatile("s_getreg_b32 %0, hwreg(HW_REG_XCC_ID)" : "=s"(xcc));
        if (tid == 0) {
            __hip_atomic_store(&xflag[grp * 32 + w], xcc + 1, __ATOMIC_RELAXED,
                               __HIP_MEMORY_SCOPE_SYSTEM);
        }
        if (wv == 0) {
            int v;
            for (;;) {
                v = __hip_atomic_load(&xflag[grp * 32 + (lane & 31)], __ATOMIC_RELAXED,
                                      __HIP_MEMORY_SCOPE_SYSTEM);
                if (__all(v != 0)) break;
                __builtin_amdgcn_s_sleep(2);
            }
            int v0 = __shfl(v, 0, 64);
            if (lane == 0) use_local_sh = __all(v == v0) ? 1 : 0;
        }
    }

    // one-time: B fragments into registers (128 regs/lane, AGPR-backed)
    // Bf[i*2+gsub] = B-frag for kstep kq*16+i, gate 2gp+gsub.
    bf16x8 Bf[32];
    {
        const unsigned short* wb = Wt + (size_t)(((w * 2 + gp) * 4 + kq) * 32) * 512
                                      + (size_t)lane * 8;
        #pragma unroll
        for (int t = 0; t < 32; ++t)
            Bf[t] = *(const bf16x8*)(wb + t * 512);
    }
    // one-time: XW slice into LDS
    if (tid < 384) {
        int tok = tid >> 7, g = (tid >> 5) & 3, jl = tid & 31;
        xwl[tid] = XW[(tok * 4 + g) * HID + w * 32 + jl];
    }
    // one-time: token table into LDS (byte-packed)
    #pragma unroll
    for (int it = 0; it < 32; ++it) {
        int flat = it * 512 + tid;                 // 16384 tokens
        int row  = flat >> 9;
        int col  = flat & 511;
        xtok[flat] = (unsigned char)x[(grp * 32 + row) * T_SEQ + col];
    }
    __syncthreads();
    const bool use_local = (use_local_sh != 0);

    // elementwise ownership: thread -> row = tid>>4, cols jc2*2..+2
    const int erow = tid >> 4;
    const int jc2  = tid & 15;
    float cst[2] = {0.f, 0.f};
    const unsigned short* hb = (const unsigned short*)hbuf32;

    for (int s = 0; s < T_SEQ; ++s) {
        // ---- wait for h(s) from all 32 group members (flags start at 0) ----
        if (s > 0) {
            if (wv == 0) {
                const int fidx = grp * 32 + (lane & 31);
                if (use_local) {
                    while (__hip_atomic_load(&flags[fidx], __ATOMIC_RELAXED,
                                             __HIP_MEMORY_SCOPE_AGENT) < s)
                        __builtin_amdgcn_s_sleep(1);
                } else {
                    while (__hip_atomic_load(&flags[fidx], __ATOMIC_RELAXED,
                                             __HIP_MEMORY_SCOPE_SYSTEM) < s)
                        __builtin_amdgcn_s_sleep(1);
                }
            }
            __syncthreads();
        }

        // ---- GEMM: A-fragments straight from global (L2), 2 gates per A ----
        // A-frag for kstep kk: lane (m32,hv5) reads h[row=grp*32+m32]
        // [cols kk*16 + hv5*8 .. +8] = one 16 B contiguous load.
        const unsigned short* hp = hb + (size_t)(s & 1) * (BATCH * HID)
                                 + ((grp * 32 + m32) * HID + kq * 256 + hv5 * 8);
        floatx16 acc0 = {0.f,0.f,0.f,0.f,0.f,0.f,0.f,0.f,0.f,0.f,0.f,0.f,0.f,0.f,0.f,0.f};
        floatx16 acc1 = {0.f,0.f,0.f,0.f,0.f,0.f,0.f,0.f,0.f,0.f,0.f,0.f,0.f,0.f,0.f,0.f};
        if (use_local) {
            // invalidate (write-through) vector L1: stale lines from step s-2
            asm volatile("buffer_inv" ::: "memory");
            #pragma unroll
            for (int i = 0; i < 16; ++i) {
                bf16x8 a = *(const bf16x8*)(hp + i * 16);
                acc0 = __builtin_amdgcn_mfma_f32_32x32x16_bf16(a, Bf[2 * i],     acc0, 0, 0, 0);
                acc1 = __builtin_amdgcn_mfma_f32_32x32x16_bf16(a, Bf[2 * i + 1], acc1, 0, 0, 0);
            }
        } else {
            #pragma unroll
            for (int i = 0; i < 16; ++i) {
                union { unsigned long long q[2]; bf16x8 a; } u;
                const unsigned long long* qp = (const unsigned long long*)(hp + i * 16);
                u.q[0] = __hip_atomic_load(qp,     __ATOMIC_RELAXED, __HIP_MEMORY_SCOPE_SYSTEM);
                u.q[1] = __hip_atomic_load(qp + 1, __ATOMIC_RELAXED, __HIP_MEMORY_SCOPE_SYSTEM);
                acc0 = __builtin_amdgcn_mfma_f32_32x32x16_bf16(u.a, Bf[2 * i],     acc0, 0, 0, 0);
                acc1 = __builtin_amdgcn_mfma_f32_32x32x16_bf16(u.a, Bf[2 * i + 1], acc1, 0, 0, 0);
            }
        }

        // ---- scatter partials (col=lane&31, row=(reg&3)+8*(reg>>2)+4*hv5) ----
        {
            float* gb0 = &gbuf[(size_t)((gp * 2 + 0) * 4 + kq) * 1152];
            float* gb1 = &gbuf[(size_t)((gp * 2 + 1) * 4 + kq) * 1152];
            #pragma unroll
            for (int reg = 0; reg < 16; ++reg) {
                int row = (reg & 3) + 8 * (reg >> 2) + 4 * hv5;
                gb0[row * 36 + m32] = acc0[reg];
                gb1[row * 36 + m32] = acc1[reg];
            }
        }
        __syncthreads();

        // ---- elementwise LSTM cell update, h(s+1) out ----
        {
            int tk = xtok[erow * 512 + s];
            const float* xb = &xwl[tk * 128];
            const int go = erow * 36 + jc2 * 2;
            #define GSUM(g) ( *(const floatx2*)&gbuf[((g) * 4 + 0) * 1152 + go] \
                            + *(const floatx2*)&gbuf[((g) * 4 + 1) * 1152 + go] \
                            + *(const floatx2*)&gbuf[((g) * 4 + 2) * 1152 + go] \
                            + *(const floatx2*)&gbuf[((g) * 4 + 3) * 1152 + go] )
            floatx2 ag = GSUM(0);
            floatx2 ai = GSUM(1);
            floatx2 af = GSUM(2);
            floatx2 ao = GSUM(3);
            #undef GSUM
            floatx2 xg = *(const floatx2*)&xb[0 * 32 + jc2 * 2];
            floatx2 xi = *(const floatx2*)&xb[1 * 32 + jc2 * 2];
            floatx2 xf = *(const floatx2*)&xb[2 * 32 + jc2 * 2];
            floatx2 xo = *(const floatx2*)&xb[3 * 32 + jc2 * 2];
            unsigned int hvv[2];
            #pragma unroll
            for (int u = 0; u < 2; ++u) {
                float g  = tanh_fast(ag[u] + xg[u]);
                float ii = sig_fast(ai[u] + xi[u]);
                float ff = sig_fast(af[u] + xf[u]);
                float oo = sig_fast(ao[u] + xo[u]);
                float cn = g * ii + cst[u] * ff;
                float h  = tanh_fast(cn) * oo;
                cst[u]   = (tk != 0) ? cn : 0.0f;   // pad = ((x+1)//2) in {0,1,1}
                hvv[u]   = f2bf(h);
            }
            unsigned int* hnext = hbuf32 + (size_t)((s + 1) & 1) * (BATCH * HID / 2);
            unsigned int* hpst = &hnext[((grp * 32 + erow) * HID + w * 32 + jc2 * 2) >> 1];
            unsigned int hval = hvv[0] | (hvv[1] << 16);
            if (use_local) {
                // plain write-back store into the shared XCD L2 (no LLC RTT)
                __hip_atomic_store(hpst, hval, __ATOMIC_RELAXED, __HIP_MEMORY_SCOPE_WORKGROUP);
            } else {
                __hip_atomic_store(hpst, hval, __ATOMIC_RELAXED, __HIP_MEMORY_SCOPE_SYSTEM);
            }
        }
        // syncthreads drains each wave's vmcnt before s_barrier => on exit, all
        // h stores of this WG are complete at their coherence point (L2 local /
        // LLC fallback) before the flag is published.
        __syncthreads();

        if (s < T_SEQ - 1 && tid == 0) {
            if (use_local) {
                __hip_atomic_store(&flags[grp * 32 + w], s + 1,
                                   __ATOMIC_RELAXED, __HIP_MEMORY_SCOPE_WORKGROUP);
            } else {
                __hip_atomic_store(&flags[grp * 32 + w], s + 1,
                                   __ATOMIC_RELAXED, __HIP_MEMORY_SCOPE_SYSTEM);
            }
        }
    }
}

// -------------------- projection + log_softmax over batch dim ---------------
__global__ void proj_kernel(const unsigned short* __restrict__ h,
                            const float* __restrict__ wph, const float* __restrict__ bp,
                            float* __restrict__ out) {
    __shared__ float wl[HID * NCLS];
    __shared__ float red[256];
    int tid = threadIdx.x;      // = batch row
    for (int i = tid; i < HID * NCLS; i += 256) wl[i] = wph[i];
    __syncthreads();
    float p[NCLS];
    #pragma unroll
    for (int c2 = 0; c2 < NCLS; ++c2) p[c2] = bp[c2];
    const unsigned short* hr = h + tid * HID;
    for (int k0 = 0; k0 < HID / 8; ++k0) {
        bf16x8 hv = *(const bf16x8*)(hr + k0 * 8);
        #pragma unroll
        for (int j = 0; j < 8; ++j) {
            float hk = (float)hv[j];
            #pragma unroll
            for (int c2 = 0; c2 < NCLS; ++c2) p[c2] += hk * wl[(k0 * 8 + j) * NCLS + c2];
        }
    }
    for (int c2 = 0; c2 < NCLS; ++c2) {
        red[tid] = p[c2];
        __syncthreads();
        for (int s = 128; s > 0; s >>= 1) {
            if (tid < s) red[tid] = fmaxf(red[tid], red[tid + s]);
            __syncthreads();
        }
        float mx = red[0];
        __syncthreads();
        red[tid] = __expf(p[c2] - mx);
        __syncthreads();
        for (int s = 128; s > 0; s >>= 1) {
            if (tid < s) red[tid] += red[tid + s];
            __syncthreads();
        }
        float lse = mx + __logf(red[0]);
        __syncthreads();
        out[tid * NCLS + c2] = p[c2] - lse;
    }
}

// ----------------------------------------------------------------------------
extern "C" void kernel_launch(void* const* d_in, const int* in_sizes, int n_in,
                              void* d_out, int out_size, void* d_ws, size_t ws_size,
                              hipStream_t stream) {
    const int*   x    = (const int*)d_in[0];
    const float* emb  = (const float*)d_in[1];
    const float* wgx  = (const float*)d_in[2];
    const float* wgh  = (const float*)d_in[3];
    const float* bg_  = (const float*)d_in[4];
    const float* wix  = (const float*)d_in[5];
    const float* wih  = (const float*)d_in[6];
    const float* bi_  = (const float*)d_in[7];
    const float* wfx  = (const float*)d_in[8];
    const float* wfh  = (const float*)d_in[9];
    const float* bf_  = (const float*)d_in[10];
    const float* wox  = (const float*)d_in[11];
    const float* woh  = (const float*)d_in[12];
    const float* bo_  = (const float*)d_in[13];
    const float* wph  = (const float*)d_in[14];
    const float* bp_  = (const float*)d_in[15];
    float* out = (float*)d_out;

    char* wsp = (char*)d_ws;
    int*            flags = (int*)wsp;                                      // 4 KB
    int*            xflag = (int*)(wsp + 4096);                             // 4 KB
    float*          XW    = (float*)(wsp + 8192);                           // 48 KB
    unsigned short* Wt    = (unsigned short*)(wsp + 8192 + 49152);          // 8 MB
    unsigned int*   hbuf32= (unsigned int*)(wsp + 8192 + 49152 + 8388608);  // 1 MB

    hipMemsetAsync(flags, 0, 8192, stream);                                  // flags+xflag
    hipMemsetAsync(hbuf32, 0, BATCH * HID * sizeof(unsigned short), stream); // h0 = 0

    prep_xw_kernel<<<48, 256, 0, stream>>>(emb, wgx, wix, wfx, wox,
                                           bg_, bi_, bf_, bo_, XW);
    prep_w_kernel<<<8192, 64, 0, stream>>>(wgh, wih, wfh, woh, Wt);

    void* args[] = { (void*)&x, (void*)&XW, (void*)&Wt, (void*)&hbuf32,
                     (void*)&flags, (void*)&xflag };
    hipError_t cerr = hipLaunchCooperativeKernel((void*)lstm_kernel, dim3(256), dim3(512),
                                                 args, 0, stream);
    if (cerr != hipSuccess) {
        // Fallback: plain launch. The flag protocol needs only co-residency,
        // which grid=256 at 1 WG/CU provides.
        lstm_kernel<<<dim3(256), dim3(512), 0, stream>>>(x, XW, Wt, hbuf32, flags, xflag);
    }

    proj_kernel<<<1, 256, 0, stream>>>((const unsigned short*)hbuf32, wph, bp_, out);
}

// Round 3
// 1882.978 us; speedup vs baseline: 1.4037x; 1.4037x over previous
//
#include <hip/hip_runtime.h>
#include <hip/hip_bf16.h>

#define T_SEQ 512
#define BATCH 256
#define HID   1024
#define EMBD  256
#define NCLS  10

typedef __bf16 bf16x8 __attribute__((ext_vector_type(8)));
typedef float  floatx16 __attribute__((ext_vector_type(16)));
typedef float  floatx2 __attribute__((ext_vector_type(2)));
typedef unsigned short ushortx8 __attribute__((ext_vector_type(8)));

__device__ __forceinline__ unsigned int f2bf(float f) {
    unsigned int u = __builtin_bit_cast(unsigned int, f);
    u += 0x7fffu + ((u >> 16) & 1u);
    return u >> 16;
}
__device__ __forceinline__ float sig_fast(float x) {
    return __builtin_amdgcn_rcpf(1.0f + __expf(-x));
}
__device__ __forceinline__ float tanh_fast(float x) {
    return 1.0f - 2.0f * __builtin_amdgcn_rcpf(1.0f + __expf(2.0f * x));
}

// -------------------- prep: XW[tok][gate][n] = emb[tok] @ Wx_gate + b_gate ---
__global__ void prep_xw_kernel(const float* __restrict__ emb,
                               const float* __restrict__ wgx, const float* __restrict__ wix,
                               const float* __restrict__ wfx, const float* __restrict__ wox,
                               const float* __restrict__ bg,  const float* __restrict__ bi,
                               const float* __restrict__ bf,  const float* __restrict__ bo,
                               float* __restrict__ XW) {
    int gid = blockIdx.x * blockDim.x + threadIdx.x;     // 3*4*1024 = 12288
    if (gid >= 3 * 4 * HID) return;
    int tok  = gid >> 12;
    int gate = (gid >> 10) & 3;
    int n    = gid & 1023;
    const float* W = gate == 0 ? wgx : gate == 1 ? wix : gate == 2 ? wfx : wox;
    const float* B = gate == 0 ? bg  : gate == 1 ? bi  : gate == 2 ? bf  : bo;
    float acc = B[n];
    const float* e = emb + tok * EMBD;
    for (int k = 0; k < EMBD; ++k) acc += e[k] * W[k * HID + n];
    XW[gid] = acc;
}

// ---- prep: Wt in 32x32x16 MFMA B-fragment order, (gate-pair, k-quarter) waves.
// Wave (w, gp, kq) handles gates {2gp, 2gp+1} over ksteps kk = kq*16 + i.
// frag = (((w*2+gp)*4+kq)*16 + i)*2 + gsub ; Wt[frag*512 + lane*8 + e]
//   = bf16( W_{2gp+gsub}[k = kk*16 + (lane>>5)*8 + e][j = w*32 + (lane&31)] )
__global__ void prep_w_kernel(const float* __restrict__ wgh, const float* __restrict__ wih,
                              const float* __restrict__ wfh, const float* __restrict__ woh,
                              unsigned short* __restrict__ Wt) {
    int bid  = blockIdx.x;                // 8192 = w(32) x gp(2) x kq(4) x i(16) x gsub(2)
    int gsub = bid & 1;
    int i    = (bid >> 1) & 15;
    int kq   = (bid >> 5) & 3;
    int gp   = (bid >> 7) & 1;
    int w    = bid >> 8;
    int g    = gp * 2 + gsub;
    const float* W = g == 0 ? wgh : g == 1 ? wih : g == 2 ? wfh : woh;
    int lane = threadIdx.x;               // 64
    int j    = w * 32 + (lane & 31);
    int kk   = kq * 16 + i;
    int k0   = kk * 16 + (lane >> 5) * 8;
    ushortx8 o8;
    #pragma unroll
    for (int e = 0; e < 8; ++e) o8[e] = (unsigned short)f2bf(W[(k0 + e) * HID + j]);
    int frag = (((w * 2 + gp) * 4 + kq) * 16 + i) * 2 + gsub;
    *(ushortx8*)&Wt[frag * 512 + lane * 8] = o8;
}

// -------------------- persistent recurrent kernel ---------------------------
// 256 WGs x 512 threads. grp = blockIdx%8 owns 32 batch rows; w = blockIdx/8
// owns 32 hidden cols.
//
// R9 (resubmitted after infra failure): R7's proven h-exchange + LDS staging
// (bulk qword loads L2->VGPR->LDS, latency hidden, placement-safe fallback,
// NO buffer_inv), combined with R8's (gate-pair gp, k-quarter kq) wave
// decomposition:
//  - each staged A-fragment ds_read feeds TWO MFMAs (gates 2gp, 2gp+1):
//    GEMM-phase LDS read traffic halves, 256 KB -> 128 KB per step.
//  - per-wave accumulator splits into two independent 16-deep MFMA chains
//    (was one 32-deep serial chain): half the latency-chain.
// R8 post-mortem: direct-L2 A-loads put L2 RTT inside the MFMA chain and
// buffer_inv defeated L1 (2x L2 traffic); fallback (system-scope in-loop
// loads) was a 16x disaster mode. All three reverted here.
// LDS: 66048 + 73728 + 1536 + 16384 + 4 = 157700 B < 160 KiB, 1 WG/CU.
__global__ __launch_bounds__(512, 2)
void lstm_kernel(const int* __restrict__ x, const float* __restrict__ XW,
                 const unsigned short* __restrict__ Wt,
                 unsigned int* __restrict__ hbuf32, int* __restrict__ flags,
                 int* __restrict__ xflag) {
    __shared__ unsigned short hs[32 * 1032];      // h stage, +8 shorts pad (66048 B)
    __shared__ float gbuf[16 * 32 * 36];          // [gate][kq][row][col+pad] (73728 B)
    __shared__ float xwl[384];                    // [tok][gate][32 cols]     (1536 B)
    __shared__ unsigned char xtok[32 * 512];      // tokens, byte-packed      (16384 B)
    __shared__ int use_local_sh;

    const int tid  = threadIdx.x;
    const int grp  = blockIdx.x & 7;
    const int w    = blockIdx.x >> 3;
    const int wv   = tid >> 6;
    const int gp   = wv >> 2;                  // gate pair: gates {2gp, 2gp+1}
    const int kq   = wv & 3;                   // k-quarter: kk in [kq*16, kq*16+16)
    const int lane = tid & 63;
    const int m32  = lane & 31;
    const int hv5  = lane >> 5;

    // ---- XCD-locality check (one-time, system-scope => placement-safe) ----
    {
        int xcc = 0;
        asm volatile("s_getreg_b32 %0, hwreg(HW_REG_XCC_ID)" : "=s"(xcc));
        if (tid == 0) {
            __hip_atomic_store(&xflag[grp * 32 + w], xcc + 1, __ATOMIC_RELAXED,
                               __HIP_MEMORY_SCOPE_SYSTEM);
        }
        if (wv == 0) {
            int v;
            for (;;) {
                v = __hip_atomic_load(&xflag[grp * 32 + (lane & 31)], __ATOMIC_RELAXED,
                                      __HIP_MEMORY_SCOPE_SYSTEM);
                if (__all(v != 0)) break;
                __builtin_amdgcn_s_sleep(2);
            }
            int v0 = __shfl(v, 0, 64);
            if (lane == 0) use_local_sh = __all(v == v0) ? 1 : 0;
        }
    }

    // one-time: B fragments into registers (128 regs/lane, AGPR-backed)
    // Bf[i*2+gsub] = B-frag for kstep kq*16+i, gate 2gp+gsub.
    bf16x8 Bf[32];
    {
        const unsigned short* wb = Wt + (size_t)(((w * 2 + gp) * 4 + kq) * 32) * 512
                                      + (size_t)lane * 8;
        #pragma unroll
        for (int t = 0; t < 32; ++t)
            Bf[t] = *(const bf16x8*)(wb + t * 512);
    }
    // one-time: XW slice into LDS
    if (tid < 384) {
        int tok = tid >> 7, g = (tid >> 5) & 3, jl = tid & 31;
        xwl[tid] = XW[(tok * 4 + g) * HID + w * 32 + jl];
    }
    // one-time: token table into LDS (byte-packed)
    #pragma unroll
    for (int it = 0; it < 32; ++it) {
        int flat = it * 512 + tid;                 // 16384 tokens
        int row  = flat >> 9;
        int col  = flat & 511;
        xtok[flat] = (unsigned char)x[(grp * 32 + row) * T_SEQ + col];
    }
    __syncthreads();
    const bool use_local = (use_local_sh != 0);

    // elementwise ownership: thread -> row = tid>>4, cols jc2*2..+2
    const int erow = tid >> 4;
    const int jc2  = tid & 15;
    float cst[2] = {0.f, 0.f};
    unsigned long long* hs64 = (unsigned long long*)hs;

    for (int s = 0; s < T_SEQ; ++s) {
        // ---- wait for h(s) from all 32 group members (flags start at 0) ----
        if (s > 0) {
            if (wv == 0) {
                const int fidx = grp * 32 + (lane & 31);
                if (use_local) {
                    while (__hip_atomic_load(&flags[fidx], __ATOMIC_RELAXED,
                                             __HIP_MEMORY_SCOPE_AGENT) < s)
                        __builtin_amdgcn_s_sleep(1);
                } else {
                    while (__hip_atomic_load(&flags[fidx], __ATOMIC_RELAXED,
                                             __HIP_MEMORY_SCOPE_SYSTEM) < s)
                        __builtin_amdgcn_s_sleep(1);
                }
            }
            __syncthreads();
        }

        // ---- stage h(s)[32 rows x 256 qwords] into padded LDS ----
        const unsigned long long* hp64 = (const unsigned long long*)
            (hbuf32 + (size_t)(s & 1) * (BATCH * HID / 2)) + (size_t)grp * 32 * 256;
        {
            unsigned long long tmp[16];
            if (use_local) {
                #pragma unroll
                for (int it = 0; it < 16; ++it) {
                    int flat = it * 512 + tid;         // 8192 qwords
                    tmp[it] = __hip_atomic_load(&hp64[(flat >> 8) * 256 + (flat & 255)],
                                                __ATOMIC_RELAXED, __HIP_MEMORY_SCOPE_AGENT);
                }
            } else {
                #pragma unroll
                for (int it = 0; it < 16; ++it) {
                    int flat = it * 512 + tid;
                    tmp[it] = __hip_atomic_load(&hp64[(flat >> 8) * 256 + (flat & 255)],
                                                __ATOMIC_RELAXED, __HIP_MEMORY_SCOPE_SYSTEM);
                }
            }
            #pragma unroll
            for (int it = 0; it < 16; ++it) {
                int flat = it * 512 + tid;
                hs64[(flat >> 8) * 258 + (flat & 255)] = tmp[it];
            }
        }
        __syncthreads();

        // ---- GEMM: 32x32 tile, 2 gates per A-fragment, B from registers ----
        // A-frag for kstep kk=kq*16+i: lane (m32,hv5) reads hs row m32,
        // cols kq*256 + i*16 + hv5*8 (one 16 B ds_read_b128).
        floatx16 acc0 = {0.f,0.f,0.f,0.f,0.f,0.f,0.f,0.f,0.f,0.f,0.f,0.f,0.f,0.f,0.f,0.f};
        floatx16 acc1 = {0.f,0.f,0.f,0.f,0.f,0.f,0.f,0.f,0.f,0.f,0.f,0.f,0.f,0.f,0.f,0.f};
        const unsigned short* ap = hs + m32 * 1032 + kq * 256 + hv5 * 8;
        #pragma unroll
        for (int i = 0; i < 16; ++i) {
            bf16x8 a = *(const bf16x8*)(ap + i * 16);
            acc0 = __builtin_amdgcn_mfma_f32_32x32x16_bf16(a, Bf[2 * i],     acc0, 0, 0, 0);
            acc1 = __builtin_amdgcn_mfma_f32_32x32x16_bf16(a, Bf[2 * i + 1], acc1, 0, 0, 0);
        }

        // ---- scatter partials (col=lane&31, row=(reg&3)+8*(reg>>2)+4*hv5) ----
        {
            float* gb0 = &gbuf[(size_t)((gp * 2 + 0) * 4 + kq) * 1152];
            float* gb1 = &gbuf[(size_t)((gp * 2 + 1) * 4 + kq) * 1152];
            #pragma unroll
            for (int reg = 0; reg < 16; ++reg) {
                int row = (reg & 3) + 8 * (reg >> 2) + 4 * hv5;
                gb0[row * 36 + m32] = acc0[reg];
                gb1[row * 36 + m32] = acc1[reg];
            }
        }
        __syncthreads();

        // ---- elementwise LSTM cell update, h(s+1) out ----
        {
            int tk = xtok[erow * 512 + s];
            const float* xb = &xwl[tk * 128];
            const int go = erow * 36 + jc2 * 2;
            #define GSUM(g) ( *(const floatx2*)&gbuf[((g) * 4 + 0) * 1152 + go] \
                            + *(const floatx2*)&gbuf[((g) * 4 + 1) * 1152 + go] \
                            + *(const floatx2*)&gbuf[((g) * 4 + 2) * 1152 + go] \
                            + *(const floatx2*)&gbuf[((g) * 4 + 3) * 1152 + go] )
            floatx2 ag = GSUM(0);
            floatx2 ai = GSUM(1);
            floatx2 af = GSUM(2);
            floatx2 ao = GSUM(3);
            #undef GSUM
            floatx2 xg = *(const floatx2*)&xb[0 * 32 + jc2 * 2];
            floatx2 xi = *(const floatx2*)&xb[1 * 32 + jc2 * 2];
            floatx2 xf = *(const floatx2*)&xb[2 * 32 + jc2 * 2];
            floatx2 xo = *(const floatx2*)&xb[3 * 32 + jc2 * 2];
            unsigned int hvv[2];
            #pragma unroll
            for (int u = 0; u < 2; ++u) {
                float g  = tanh_fast(ag[u] + xg[u]);
                float ii = sig_fast(ai[u] + xi[u]);
                float ff = sig_fast(af[u] + xf[u]);
                float oo = sig_fast(ao[u] + xo[u]);
                float cn = g * ii + cst[u] * ff;
                float h  = tanh_fast(cn) * oo;
                cst[u]   = (tk != 0) ? cn : 0.0f;   // pad = ((x+1)//2) in {0,1,1}
                hvv[u]   = f2bf(h);
            }
            unsigned int* hnext = hbuf32 + (size_t)((s + 1) & 1) * (BATCH * HID / 2);
            unsigned int* hp = &hnext[((grp * 32 + erow) * HID + w * 32 + jc2 * 2) >> 1];
            unsigned int hval = hvv[0] | (hvv[1] << 16);
            if (use_local) {
                // plain write-back store into the shared XCD L2 (no LLC RTT)
                __hip_atomic_store(hp, hval, __ATOMIC_RELAXED, __HIP_MEMORY_SCOPE_WORKGROUP);
            } else {
                __hip_atomic_store(hp, hval, __ATOMIC_RELAXED, __HIP_MEMORY_SCOPE_SYSTEM);
            }
        }
        // syncthreads drains each wave's vmcnt before s_barrier => on exit, all
        // h stores of this WG are complete at their coherence point (L2 local /
        // LLC fallback) before the flag is published.
        __syncthreads();

        if (s < T_SEQ - 1 && tid == 0) {
            if (use_local) {
                __hip_atomic_store(&flags[grp * 32 + w], s + 1,
                                   __ATOMIC_RELAXED, __HIP_MEMORY_SCOPE_WORKGROUP);
            } else {
                __hip_atomic_store(&flags[grp * 32 + w], s + 1,
                                   __ATOMIC_RELAXED, __HIP_MEMORY_SCOPE_SYSTEM);
            }
        }
    }
}

// -------------------- projection + log_softmax over batch dim ---------------
__global__ void proj_kernel(const unsigned short* __restrict__ h,
                            const float* __restrict__ wph, const float* __restrict__ bp,
                            float* __restrict__ out) {
    __shared__ float wl[HID * NCLS];
    __shared__ float red[256];
    int tid = threadIdx.x;      // = batch row
    for (int i = tid; i < HID * NCLS; i += 256) wl[i] = wph[i];
    __syncthreads();
    float p[NCLS];
    #pragma unroll
    for (int c2 = 0; c2 < NCLS; ++c2) p[c2] = bp[c2];
    const unsigned short* hr = h + tid * HID;
    for (int k0 = 0; k0 < HID / 8; ++k0) {
        bf16x8 hv = *(const bf16x8*)(hr + k0 * 8);
        #pragma unroll
        for (int j = 0; j < 8; ++j) {
            float hk = (float)hv[j];
            #pragma unroll
            for (int c2 = 0; c2 < NCLS; ++c2) p[c2] += hk * wl[(k0 * 8 + j) * NCLS + c2];
        }
    }
    for (int c2 = 0; c2 < NCLS; ++c2) {
        red[tid] = p[c2];
        __syncthreads();
        for (int s = 128; s > 0; s >>= 1) {
            if (tid < s) red[tid] = fmaxf(red[tid], red[tid + s]);
            __syncthreads();
        }
        float mx = red[0];
        __syncthreads();
        red[tid] = __expf(p[c2] - mx);
        __syncthreads();
        for (int s = 128; s > 0; s >>= 1) {
            if (tid < s) red[tid] += red[tid + s];
            __syncthreads();
        }
        float lse = mx + __logf(red[0]);
        __syncthreads();
        out[tid * NCLS + c2] = p[c2] - lse;
    }
}

// ----------------------------------------------------------------------------
extern "C" void kernel_launch(void* const* d_in, const int* in_sizes, int n_in,
                              void* d_out, int out_size, void* d_ws, size_t ws_size,
                              hipStream_t stream) {
    const int*   x    = (const int*)d_in[0];
    const float* emb  = (const float*)d_in[1];
    const float* wgx  = (const float*)d_in[2];
    const float* wgh  = (const float*)d_in[3];
    const float* bg_  = (const float*)d_in[4];
    const float* wix  = (const float*)d_in[5];
    const float* wih  = (const float*)d_in[6];
    const float* bi_  = (const float*)d_in[7];
    const float* wfx  = (const float*)d_in[8];
    const float* wfh  = (const float*)d_in[9];
    const float* bf_  = (const float*)d_in[10];
    const float* wox  = (const float*)d_in[11];
    const float* woh  = (const float*)d_in[12];
    const float* bo_  = (const float*)d_in[13];
    const float* wph  = (const float*)d_in[14];
    const float* bp_  = (const float*)d_in[15];
    float* out = (float*)d_out;

    char* wsp = (char*)d_ws;
    int*            flags = (int*)wsp;                                      // 4 KB
    int*            xflag = (int*)(wsp + 4096);                             // 4 KB
    float*          XW    = (float*)(wsp + 8192);                           // 48 KB
    unsigned short* Wt    = (unsigned short*)(wsp + 8192 + 49152);          // 8 MB
    unsigned int*   hbuf32= (unsigned int*)(wsp + 8192 + 49152 + 8388608);  // 1 MB

    hipMemsetAsync(flags, 0, 8192, stream);                                  // flags+xflag
    hipMemsetAsync(hbuf32, 0, BATCH * HID * sizeof(unsigned short), stream); // h0 = 0

    prep_xw_kernel<<<48, 256, 0, stream>>>(emb, wgx, wix, wfx, wox,
                                           bg_, bi_, bf_, bo_, XW);
    prep_w_kernel<<<8192, 64, 0, stream>>>(wgh, wih, wfh, woh, Wt);

    void* args[] = { (void*)&x, (void*)&XW, (void*)&Wt, (void*)&hbuf32,
                     (void*)&flags, (void*)&xflag };
    hipError_t cerr = hipLaunchCooperativeKernel((void*)lstm_kernel, dim3(256), dim3(512),
                                                 args, 0, stream);
    if (cerr != hipSuccess) {
        // Fallback: plain launch. The flag protocol needs only co-residency,
        // which grid=256 at 1 WG/CU provides.
        lstm_kernel<<<dim3(256), dim3(512), 0, stream>>>(x, XW, Wt, hbuf32, flags, xflag);
    }

    proj_kernel<<<1, 256, 0, stream>>>((const unsigned short*)hbuf32, wph, bp_, out);
}